// Round 8
// baseline (75.902 us; speedup 1.0000x reference)
//
#include <hip/hip_runtime.h>

#define IMG 256
#define SUBT 8            // sub-blocks per tile (face-range split, union via cond. stores)
#define CAP 1024          // per-chunk LDS lists (chunk = 1024 faces -> can't overflow)
#define DELTA 1e-3f       // conservative margin >> fp32 rounding (~2e-6)
#define SPLIT 4           // fallback kernel: row-block waves per face
#define BB_SENTINEL 0x00FF00FF   // ix0=255, ix1=0: overlaps no tile
#define DOM_MAGIC 0x5AC3E917     // non-repeating word: cannot equal byte/word-pattern poison
#define DOM_SCAN_MAX 49          // prep dom-scan cap (7x7 tiles) bounds wave divergence

// 32B per-face record: projected verts + packed conservative pixel bbox.
struct __align__(16) FaceRec { float4 a; float4 b; };
// a = (v0x, v0y, v1x, v1y); b = (v2x, v2y, bbox_bits, 0)

// One thread per (b, padded-face): zero output, project 3 verts (bit-identical
// numpy fp32 op order), write 32B record + 4B bbox word (scan prefilter), and
// flag tiles this face DOMINATES (DELTA-margin corner-interval test) with
// DOM_MAGIC. The flag is an accelerator only: tile-side dominator detection
// is unchanged, so a missing flag is always safe.
__global__ void prep_kernel(const float* __restrict__ verts,
                            const int* __restrict__ faces,
                            const float* __restrict__ cams,
                            FaceRec* __restrict__ recs,
                            int* __restrict__ bbA,
                            int* __restrict__ dom,
                            float4* __restrict__ out4, int n4,
                            int B, int V, int F, int Fp) {
    int i = blockIdx.x * blockDim.x + threadIdx.x;
    if (i < n4) out4[i] = make_float4(0.f, 0.f, 0.f, 0.f);
    if (i >= B * Fp) return;
    int b = i / Fp, fid = i - b * Fp;
    if (fid >= F) { bbA[i] = BB_SENTINEL; return; }   // padding: never overlaps
    const int* fp = faces + ((size_t)b * F + fid) * 3;
    float f  = __fadd_rn(__fmul_rn(1.0f, cams[b * 3 + 0]), 0.0f);
    float cx = cams[b * 3 + 1];
    float cy = cams[b * 3 + 2];
    float image_size = __fmul_rn(cams[1], 2.0f);  // cam[0,1] * 2.0
    float vx[3], vy[3];
    #pragma unroll
    for (int k = 0; k < 3; ++k) {
        const float* vp = verts + ((size_t)b * V + fp[k]) * 3;
        float x = vp[0], y = vp[1];
        float z = __fadd_rn(vp[2], 0.0f);
        float pxv = __fadd_rn(__fdiv_rn(__fmul_rn(f, x), z), cx);
        float pyv = __fadd_rn(__fdiv_rn(__fmul_rn(f, y), z), cy);
        vx[k] = __fsub_rn(__fmul_rn(__fdiv_rn(pxv, image_size), 2.0f), 1.0f);
        vy[k] = __fsub_rn(__fmul_rn(__fdiv_rn(pyv, image_size), 2.0f), 1.0f);
    }
    float area = __fsub_rn(
        __fmul_rn(__fsub_rn(vx[1], vx[0]), __fsub_rn(vy[2], vy[0])),
        __fmul_rn(__fsub_rn(vy[1], vy[0]), __fsub_rn(vx[2], vx[0])));
    int bb = BB_SENTINEL;
    int ix0 = 0, ix1 = -1, iy0 = 0, iy1 = -1;
    if (fabsf(area) > 1e-12f) {   // NaN-safe: NaN -> false -> culled (== ref mask)
        float xmn = fminf(vx[0], fminf(vx[1], vx[2]));
        float xmx = fmaxf(vx[0], fmaxf(vx[1], vx[2]));
        float ymn = fminf(vy[0], fminf(vy[1], vy[2]));
        float ymx = fmaxf(vy[0], fmaxf(vy[1], vy[2]));
        ix0 = max(0,       (int)floorf(xmn * 128.0f + 127.5f) - 1);
        ix1 = min(IMG - 1, (int)ceilf (xmx * 128.0f + 127.5f) + 1);
        iy0 = max(0,       (int)floorf(ymn * 128.0f + 127.5f) - 1);
        iy1 = min(IMG - 1, (int)ceilf (ymx * 128.0f + 127.5f) + 1);
        if (ix0 <= ix1 && iy0 <= iy1)
            bb = ix0 | (ix1 << 8) | (iy0 << 16) | (iy1 << 24);
    }
    bbA[i] = bb;
    recs[i].a = make_float4(vx[0], vy[0], vx[1], vy[1]);
    recs[i].b = make_float4(vx[2], vy[2], __int_as_float(bb), 0.0f);

    // --- dom-scan: flag tiles fully covered by this face ---
    if (bb == BB_SENTINEL) return;
    int tX0 = ix0 >> 4, tX1 = ix1 >> 4, tY0 = iy0 >> 4, tY1 = iy1 >> 4;
    int ntx = tX1 - tX0 + 1, nty = tY1 - tY0 + 1;
    if (ntx * nty > DOM_SCAN_MAX) return;    // cap divergence; safety net in tile
    float e0x = __fsub_rn(vx[2], vx[1]), e0y = __fsub_rn(vy[2], vy[1]);
    float e1x = __fsub_rn(vx[0], vx[2]), e1y = __fsub_rn(vy[0], vy[2]);
    float e2x = __fsub_rn(vx[1], vx[0]), e2y = __fsub_rn(vy[1], vy[0]);
    const float EXT = 0.1171875f;   // 30/256: span of a tile's pixel centers
    float ax0 = EXT * e0y, ay0 = -EXT * e0x;
    float ax1 = EXT * e1y, ay1 = -EXT * e1x;
    float ax2 = EXT * e2y, ay2 = -EXT * e2x;
    float p0 = fminf(ax0, 0.f) + fminf(ay0, 0.f), q0 = fmaxf(ax0, 0.f) + fmaxf(ay0, 0.f);
    float p1 = fminf(ax1, 0.f) + fminf(ay1, 0.f), q1 = fmaxf(ax1, 0.f) + fmaxf(ay1, 0.f);
    float p2 = fminf(ax2, 0.f) + fminf(ay2, 0.f), q2 = fmaxf(ax2, 0.f) + fmaxf(ay2, 0.f);
    for (int tty = tY0; tty <= tY1; ++tty) {
        float cy0t = (float)(2 * (tty << 4) + 1) * 0.00390625f - 1.0f;
        for (int ttx = tX0; ttx <= tX1; ++ttx) {
            float cx0t = (float)(2 * (ttx << 4) + 1) * 0.00390625f - 1.0f;
            float w0 = (cx0t - vx[1]) * e0y - (cy0t - vy[1]) * e0x;
            float w1 = (cx0t - vx[2]) * e1y - (cy0t - vy[2]) * e1x;
            float w2 = (cx0t - vx[0]) * e2y - (cy0t - vy[0]) * e2x;
            bool posIn = fminf(w0 + p0, fminf(w1 + p1, w2 + p2)) >  DELTA;
            bool negIn = fmaxf(w0 + q0, fmaxf(w1 + q1, w2 + q2)) < -DELTA;
            if (posIn || negIn)
                dom[(b << 8) + (tty << 4) + ttx] = DOM_MAGIC;  // benign race
        }
    }
}

// 4-row exact test: lane's column px, rows ybase+4k (k=0..3). The column
// terms a_j are the identical __fmul_rn(__fsub_rn(px,v),e) subtrees of the
// reference expression, so each row's w is bit-identical to the reference.
__device__ __forceinline__ unsigned test4(float4 ra, float4 rc,
                                          float px, int ybase) {
    float v0x = ra.x, v0y = ra.y, v1x = ra.z, v1y = ra.w;
    float v2x = rc.x, v2y = rc.y;
    float e0x = __fsub_rn(v2x, v1x), e0y = __fsub_rn(v2y, v1y);
    float e1x = __fsub_rn(v0x, v2x), e1y = __fsub_rn(v0y, v2y);
    float e2x = __fsub_rn(v1x, v0x), e2y = __fsub_rn(v1y, v0y);
    float a0 = __fmul_rn(__fsub_rn(px, v1x), e0y);
    float a1 = __fmul_rn(__fsub_rn(px, v2x), e1y);
    float a2 = __fmul_rn(__fsub_rn(px, v0x), e2y);
    unsigned m = 0;
    #pragma unroll
    for (int k = 0; k < 4; ++k) {
        float py = (float)(2 * (ybase + 4 * k) + 1) * 0.00390625f - 1.0f;
        float w0 = __fsub_rn(a0, __fmul_rn(__fsub_rn(py, v1y), e0x));
        float w1 = __fsub_rn(a1, __fmul_rn(__fsub_rn(py, v2y), e1x));
        float w2 = __fsub_rn(a2, __fmul_rn(__fsub_rn(py, v0y), e2x));
        float mn = fminf(w0, fminf(w1, w2));
        float mx = fmaxf(w0, fmaxf(w1, w2));
        if ((mn >= 0.f) || (mx <= 0.f)) m |= 1u << k;
    }
    return m;
}

// Wave-split raster: wave w takes list entries w, w+4, w+8, ... Eager x4
// batched loads (8 float4s in flight) break the load-latency chain.
__device__ __forceinline__ void raster_ws(const int* __restrict__ lst, int n,
        const FaceRec* __restrict__ rb, float px, int ybase, int w,
        unsigned& mask) {
    int i = w;
    for (; i + 12 < n; i += 16) {
        if (__all((int)(mask == 0xFu))) return;
        int f0 = lst[i], f1 = lst[i + 4], f2 = lst[i + 8], f3 = lst[i + 12];
        float4 a0 = rb[f0].a, b0 = rb[f0].b;
        float4 a1 = rb[f1].a, b1 = rb[f1].b;
        float4 a2 = rb[f2].a, b2 = rb[f2].b;
        float4 a3 = rb[f3].a, b3 = rb[f3].b;
        mask |= test4(a0, b0, px, ybase);
        mask |= test4(a1, b1, px, ybase);
        mask |= test4(a2, b2, px, ybase);
        mask |= test4(a3, b3, px, ybase);
    }
    for (; i < n; i += 4) {
        int fid = lst[i];
        float4 ra = rb[fid].a, rc = rb[fid].b;
        mask |= test4(ra, rc, px, ybase);
    }
}

// SUBT blocks per 16x16 tile; block `sub` scans face-quads [sub*Q, sub*Q+Q).
// FAST EXIT: if prep flagged the tile as dominated, sub 0 writes 256 ones and
// everyone returns (no scanning). Else the proven round-6 3-phase loop:
//   A: bbox prefilter -> L1;  B: classify (dom/out/partial) -> L2;
//   C: wave-split exact raster of L2.
// Output pre-zeroed by prep; covered pixels stored conditionally.
__global__ __launch_bounds__(256) void tile_kernel(
        const FaceRec* __restrict__ recs, const int4* __restrict__ bbq,
        const int* __restrict__ dom, float* __restrict__ out,
        int B, int F, int Fp) {
    __shared__ int L1[CAP];
    __shared__ int L2[CAP];
    __shared__ int s_c1, s_c2, s_dom, s_cov[64];
    int bid  = blockIdx.x;
    int tile = bid / SUBT;
    int sub  = bid - tile * SUBT;
    int b = tile >> 8, t = tile & 255;
    int tx0 = (t & 15) << 4, ty0 = (t >> 4) << 4;
    int tid = threadIdx.x;

    if (dom[tile] == DOM_MAGIC) {         // uniform read -> uniform exit
        if (sub == 0)
            out[((size_t)b << 16) + (ty0 + (tid >> 4)) * IMG + tx0 + (tid & 15)] = 1.0f;
        return;
    }

    int lane = tid & 63, w = tid >> 6;
    int col = lane & 15, r0 = lane >> 4;
    if (tid == 0) { s_c1 = 0; s_c2 = 0; s_dom = 0; }
    if (tid < 64) s_cov[tid] = 0;
    // pixel centers (2k+1)/256 - 1, exactly representable in fp32
    float px = (float)(2 * (tx0 + col) + 1) * 0.00390625f - 1.0f;
    int ybase = ty0 + r0;                 // this lane's rows: ybase + 4k
    float cx0 = (float)(2 * tx0 + 1) * 0.00390625f - 1.0f;
    float cy0 = (float)(2 * ty0 + 1) * 0.00390625f - 1.0f;
    int txm = tx0 + 15, tym = ty0 + 15;
    const float EXT = 0.1171875f;  // 30/256: span of the tile's pixel centers
    const FaceRec* rb = recs + (size_t)b * Fp;
    int F4 = Fp >> 2;
    const int4* qb = bbq + (size_t)b * F4;
    int Q = (F4 + SUBT - 1) / SUBT;
    int qlo = sub * Q;
    int qhi = min(F4, qlo + Q);
    unsigned mask = 0;
    bool dm = false;

    for (int q0 = qlo; q0 < qhi; q0 += 256) {
        if (tid == 0) { s_c1 = 0; s_c2 = 0; s_dom = 0; }
        __syncthreads();                  // resets visible; prev raster done
        // --- Phase A: bbox prefilter -> L1 (no vert loads) ---
        int q = q0 + tid;
        if (q < qhi) {
            int4 bb4 = qb[q];
            int fbase = q << 2;
            #pragma unroll
            for (int k = 0; k < 4; ++k) {
                int bb = (k == 0) ? bb4.x : (k == 1) ? bb4.y
                       : (k == 2) ? bb4.z : bb4.w;
                int ix0 = bb & 255, ix1 = (bb >> 8) & 255;
                int iy0 = (bb >> 16) & 255, iy1 = (bb >> 24) & 255;
                if (ix0 <= txm && ix1 >= tx0 && iy0 <= tym && iy1 >= ty0) {
                    int s = atomicAdd(&s_c1, 1);   // <= 1024/chunk == CAP
                    L1[s] = fbase + k;
                }
            }
        }
        __syncthreads();                  // L1 complete
        // --- Phase B: dense classify, 1 face/thread ---
        int n1 = s_c1;
        for (int i = tid; i < n1; i += 256) {
            int fid = L1[i];
            float4 ra = rb[fid].a;
            float4 rc = rb[fid].b;
            float v0x = ra.x, v0y = ra.y, v1x = ra.z, v1y = ra.w;
            float v2x = rc.x, v2y = rc.y;
            float e0x = __fsub_rn(v2x, v1x), e0y = __fsub_rn(v2y, v1y);
            float e1x = __fsub_rn(v0x, v2x), e1y = __fsub_rn(v0y, v2y);
            float e2x = __fsub_rn(v1x, v0x), e2y = __fsub_rn(v1y, v0y);
            // edge value at tile-corner pixel center; affine -> interval bound
            float w0 = (cx0 - v1x) * e0y - (cy0 - v1y) * e0x;
            float w1 = (cx0 - v2x) * e1y - (cy0 - v2y) * e1x;
            float w2 = (cx0 - v0x) * e2y - (cy0 - v0y) * e2x;
            float ax0 = EXT * e0y, ay0 = -EXT * e0x;
            float ax1 = EXT * e1y, ay1 = -EXT * e1x;
            float ax2 = EXT * e2y, ay2 = -EXT * e2x;
            float mn0 = w0 + fminf(ax0, 0.f) + fminf(ay0, 0.f);
            float mx0 = w0 + fmaxf(ax0, 0.f) + fmaxf(ay0, 0.f);
            float mn1 = w1 + fminf(ax1, 0.f) + fminf(ay1, 0.f);
            float mx1 = w1 + fmaxf(ax1, 0.f) + fmaxf(ay1, 0.f);
            float mn2 = w2 + fminf(ax2, 0.f) + fminf(ay2, 0.f);
            float mx2 = w2 + fmaxf(ax2, 0.f) + fmaxf(ay2, 0.f);
            bool posIn = fminf(mn0, fminf(mn1, mn2)) >  DELTA;
            bool negIn = fmaxf(mx0, fmaxf(mx1, mx2)) < -DELTA;
            if (posIn || negIn) {
                s_dom = 1;                 // benign race: all writers store 1
            } else {
                bool outz = (fminf(mx0, fminf(mx1, mx2)) < -DELTA) &&
                            (fmaxf(mn0, fmaxf(mn1, mn2)) >  DELTA);
                if (!outz) {
                    int s = atomicAdd(&s_c2, 1);   // <= n1 <= CAP
                    L2[s] = fid;
                }
            }
        }
        __syncthreads();                  // L2 + dom flag complete
        int n2 = s_c2;
        if (s_dom) { dm = true; break; }  // uniform (read after barrier)
        // --- Phase C: wave-split exact raster ---
        raster_ws(L2, n2, rb, px, ybase, w, mask);
        __syncthreads();                  // raster reads done before next reset
    }

    size_t outB = (size_t)b << 16;
    if (dm) {
        out[outB + (ty0 + (tid >> 4)) * IMG + tx0 + (tid & 15)] = 1.0f;
        return;
    }
    atomicOr(&s_cov[lane], (int)mask);
    __syncthreads();
    int row = tid >> 4, oc = tid & 15;
    int li = oc | ((row & 3) << 4), k = row >> 2;
    if ((s_cov[li] >> k) & 1)
        out[outB + (ty0 + row) * IMG + tx0 + oc] = 1.0f;
}

// ---------------- Fallback path (proven) if workspace too small ----------------
__global__ void init_kernel(const float* __restrict__ verts,
                            const float* __restrict__ cams,
                            float4* __restrict__ out4, int n4,
                            float2* __restrict__ ndc, int BV, int V) {
    int i = blockIdx.x * blockDim.x + threadIdx.x;
    if (i < n4) out4[i] = make_float4(0.f, 0.f, 0.f, 0.f);
    if (i < BV) {
        int b = i / V;
        float f  = __fadd_rn(__fmul_rn(1.0f, cams[b * 3 + 0]), 0.0f);
        float cx = cams[b * 3 + 1];
        float cy = cams[b * 3 + 2];
        float image_size = __fmul_rn(cams[1], 2.0f);
        float x = verts[3 * i + 0];
        float y = verts[3 * i + 1];
        float z = __fadd_rn(verts[3 * i + 2], 0.0f);
        float px = __fadd_rn(__fdiv_rn(__fmul_rn(f, x), z), cx);
        float py = __fadd_rn(__fdiv_rn(__fmul_rn(f, y), z), cy);
        float nx = __fsub_rn(__fmul_rn(__fdiv_rn(px, image_size), 2.0f), 1.0f);
        float ny = __fsub_rn(__fmul_rn(__fdiv_rn(py, image_size), 2.0f), 1.0f);
        ndc[i] = make_float2(nx, ny);
    }
}

__global__ __launch_bounds__(256) void raster_kernel(
        const float2* __restrict__ ndc, const int* __restrict__ faces,
        float* __restrict__ out, int B, int V, int F) {
    int gid  = blockIdx.x * blockDim.x + threadIdx.x;
    int wave = gid >> 6;
    int lane = gid & 63;
    int widx = wave >> 2;
    int sub  = wave & (SPLIT - 1);
    if (widx >= B * F) return;
    int b  = widx / F;
    const int* fp = faces + (size_t)widx * 3;
    const float2* nb = ndc + (size_t)b * V;
    float2 v0 = nb[fp[0]];
    float2 v1 = nb[fp[1]];
    float2 v2 = nb[fp[2]];
    float area = __fsub_rn(
        __fmul_rn(__fsub_rn(v1.x, v0.x), __fsub_rn(v2.y, v0.y)),
        __fmul_rn(__fsub_rn(v1.y, v0.y), __fsub_rn(v2.x, v0.x)));
    if (!(fabsf(area) > 1e-12f)) return;
    float xmn = fminf(v0.x, fminf(v1.x, v2.x));
    float xmx = fmaxf(v0.x, fmaxf(v1.x, v2.x));
    float ymn = fminf(v0.y, fminf(v1.y, v2.y));
    float ymx = fmaxf(v0.y, fmaxf(v1.y, v2.y));
    int ix0 = max(0,       (int)floorf(xmn * 128.0f + 127.5f) - 1);
    int ix1 = min(IMG - 1, (int)ceilf (xmx * 128.0f + 127.5f) + 1);
    int iy0 = max(0,       (int)floorf(ymn * 128.0f + 127.5f) - 1);
    int iy1 = min(IMG - 1, (int)ceilf (ymx * 128.0f + 127.5f) + 1);
    if (ix1 < ix0 || iy1 < iy0) return;
    int W = ix1 - ix0 + 1, H = iy1 - iy0 + 1;
    int tws = 6, bestIt = ((W + 63) >> 6) * H;
    int it;
    it = ((W + 31) >> 5) * ((H + 1) >> 1); if (it < bestIt) { bestIt = it; tws = 5; }
    it = ((W + 15) >> 4) * ((H + 3) >> 2); if (it < bestIt) { bestIt = it; tws = 4; }
    it = ((W + 7)  >> 3) * ((H + 7) >> 3); if (it < bestIt) { bestIt = it; tws = 3; }
    int TW = 1 << tws, TH = 64 >> tws;
    int dx = lane & (TW - 1), dy = lane >> tws;
    float e0x = __fsub_rn(v2.x, v1.x), e0y = __fsub_rn(v2.y, v1.y);
    float e1x = __fsub_rn(v0.x, v2.x), e1y = __fsub_rn(v0.y, v2.y);
    float e2x = __fsub_rn(v1.x, v0.x), e2y = __fsub_rn(v1.y, v0.y);
    float* outb = out + (size_t)b * IMG * IMG;
    float pxStep = (float)TW * 0.0078125f;
    for (int ty = iy0 + sub * TH; ty <= iy1; ty += SPLIT * TH) {
        int y = ty + dy;
        bool yok = (y <= iy1);
        float py = (float)(2 * y + 1) * 0.00390625f - 1.0f;
        float t0 = __fmul_rn(__fsub_rn(py, v1.y), e0x);
        float t1 = __fmul_rn(__fsub_rn(py, v2.y), e1x);
        float t2 = __fmul_rn(__fsub_rn(py, v0.y), e2x);
        float* p = outb + y * IMG + ix0 + dx;
        int x = ix0 + dx;
        float px = (float)(2 * x + 1) * 0.00390625f - 1.0f;
        for (int tx = ix0; tx <= ix1; tx += TW) {
            float w0 = __fsub_rn(__fmul_rn(__fsub_rn(px, v1.x), e0y), t0);
            float w1 = __fsub_rn(__fmul_rn(__fsub_rn(px, v2.x), e1y), t1);
            float w2 = __fsub_rn(__fmul_rn(__fsub_rn(px, v0.x), e2y), t2);
            float mn = fminf(w0, fminf(w1, w2));
            float mx = fmaxf(w0, fmaxf(w1, w2));
            bool inside = (mn >= 0.f) | (mx <= 0.f);
            if (inside & yok & (x <= ix1)) *p = 1.0f;
            px += pxStep;
            x  += TW;
            p  += TW;
        }
    }
}

extern "C" void kernel_launch(void* const* d_in, const int* in_sizes, int n_in,
                              void* d_out, int out_size, void* d_ws, size_t ws_size,
                              hipStream_t stream) {
    const float* verts = (const float*)d_in[0];
    const int*   faces = (const int*)d_in[1];
    const float* cams  = (const float*)d_in[2];
    float* out = (float*)d_out;

    int B = in_sizes[2] / 3;
    int V = in_sizes[0] / (3 * B);
    int F = in_sizes[1] / (3 * B);
    int Fp = (F + 3) & ~3;               // pad to int4-quad multiple

    size_t recsB = (size_t)B * Fp * sizeof(FaceRec);
    size_t bbB   = ((size_t)B * Fp * sizeof(int) + 255) & ~(size_t)255;
    size_t domB  = (size_t)B * 256 * sizeof(int);
    if (ws_size >= recsB + bbB + domB) {
        FaceRec* recs = (FaceRec*)d_ws;
        int* bbA = (int*)((char*)d_ws + recsB);   // recsB is 16B-aligned
        int* dom = (int*)((char*)d_ws + recsB + bbB);
        int n4 = out_size / 4;
        int nthr = B * Fp > n4 ? B * Fp : n4;
        hipLaunchKernelGGL(prep_kernel, dim3((nthr + 255) / 256), dim3(256), 0,
                           stream, verts, faces, cams, recs, bbA, dom,
                           (float4*)d_out, n4, B, V, F, Fp);
        hipLaunchKernelGGL(tile_kernel, dim3(B * 256 * SUBT), dim3(256), 0,
                           stream, recs, (const int4*)bbA, dom, out, B, F, Fp);
    } else {
        float2* ndc = (float2*)d_ws;
        int n4 = out_size / 4;
        int initThreads = n4 > B * V ? n4 : B * V;
        hipLaunchKernelGGL(init_kernel, dim3((initThreads + 255) / 256), dim3(256), 0,
                           stream, verts, cams, (float4*)d_out, n4, ndc, B * V, V);
        long long nthreads = (long long)B * F * SPLIT * 64;
        hipLaunchKernelGGL(raster_kernel, dim3((int)((nthreads + 255) / 256)),
                           dim3(256), 0, stream, ndc, faces, out, B, V, F);
    }
}

// Round 9
// 72.606 us; speedup vs baseline: 1.0454x; 1.0454x over previous
//
#include <hip/hip_runtime.h>

#define IMG 256
#define SUBT 8            // sub-blocks per tile (face-range split, union via cond. stores)
#define CAP 1024          // per-chunk LDS lists (chunk = 1024 faces -> can't overflow)
#define DELTA 1e-3f       // conservative margin >> fp32 rounding (~2e-6)
#define SPLIT 4           // fallback kernel: row-block waves per face
#define BB_SENTINEL 0x00FF00FF   // ix0=255, ix1=0: overlaps no tile

// 32B per-face record: projected verts + packed conservative pixel bbox.
struct __align__(16) FaceRec { float4 a; float4 b; };
// a = (v0x, v0y, v1x, v1y); b = (v2x, v2y, bbox_bits, 0)

// One thread per (b, padded-face): zero output, project 3 verts (bit-identical
// numpy fp32 op order), write 32B record + 4B bbox word (scan prefilter).
__global__ void prep_kernel(const float* __restrict__ verts,
                            const int* __restrict__ faces,
                            const float* __restrict__ cams,
                            FaceRec* __restrict__ recs,
                            int* __restrict__ bbA,
                            float4* __restrict__ out4, int n4,
                            int B, int V, int F, int Fp) {
    int i = blockIdx.x * blockDim.x + threadIdx.x;
    if (i < n4) out4[i] = make_float4(0.f, 0.f, 0.f, 0.f);
    if (i >= B * Fp) return;
    int b = i / Fp, fid = i - b * Fp;
    if (fid >= F) { bbA[i] = BB_SENTINEL; return; }   // padding: never overlaps
    const int* fp = faces + ((size_t)b * F + fid) * 3;
    float f  = __fadd_rn(__fmul_rn(1.0f, cams[b * 3 + 0]), 0.0f);
    float cx = cams[b * 3 + 1];
    float cy = cams[b * 3 + 2];
    float image_size = __fmul_rn(cams[1], 2.0f);  // cam[0,1] * 2.0
    float vx[3], vy[3];
    #pragma unroll
    for (int k = 0; k < 3; ++k) {
        const float* vp = verts + ((size_t)b * V + fp[k]) * 3;
        float x = vp[0], y = vp[1];
        float z = __fadd_rn(vp[2], 0.0f);
        float pxv = __fadd_rn(__fdiv_rn(__fmul_rn(f, x), z), cx);
        float pyv = __fadd_rn(__fdiv_rn(__fmul_rn(f, y), z), cy);
        vx[k] = __fsub_rn(__fmul_rn(__fdiv_rn(pxv, image_size), 2.0f), 1.0f);
        vy[k] = __fsub_rn(__fmul_rn(__fdiv_rn(pyv, image_size), 2.0f), 1.0f);
    }
    float area = __fsub_rn(
        __fmul_rn(__fsub_rn(vx[1], vx[0]), __fsub_rn(vy[2], vy[0])),
        __fmul_rn(__fsub_rn(vy[1], vy[0]), __fsub_rn(vx[2], vx[0])));
    int bb = BB_SENTINEL;
    if (fabsf(area) > 1e-12f) {   // NaN-safe: NaN -> false -> culled (== ref mask)
        float xmn = fminf(vx[0], fminf(vx[1], vx[2]));
        float xmx = fmaxf(vx[0], fmaxf(vx[1], vx[2]));
        float ymn = fminf(vy[0], fminf(vy[1], vy[2]));
        float ymx = fmaxf(vy[0], fmaxf(vy[1], vy[2]));
        int ix0 = max(0,       (int)floorf(xmn * 128.0f + 127.5f) - 1);
        int ix1 = min(IMG - 1, (int)ceilf (xmx * 128.0f + 127.5f) + 1);
        int iy0 = max(0,       (int)floorf(ymn * 128.0f + 127.5f) - 1);
        int iy1 = min(IMG - 1, (int)ceilf (ymx * 128.0f + 127.5f) + 1);
        if (ix0 <= ix1 && iy0 <= iy1)
            bb = ix0 | (ix1 << 8) | (iy0 << 16) | (iy1 << 24);
    }
    bbA[i] = bb;
    recs[i].a = make_float4(vx[0], vy[0], vx[1], vy[1]);
    recs[i].b = make_float4(vx[2], vy[2], __int_as_float(bb), 0.0f);
}

// 4-row exact test: lane's column px, rows ybase+4k (k=0..3). The column
// terms a_j are the identical __fmul_rn(__fsub_rn(px,v),e) subtrees of the
// reference expression, so each row's w is bit-identical to the reference.
__device__ __forceinline__ unsigned test4(float4 ra, float4 rc,
                                          float px, int ybase) {
    float v0x = ra.x, v0y = ra.y, v1x = ra.z, v1y = ra.w;
    float v2x = rc.x, v2y = rc.y;
    float e0x = __fsub_rn(v2x, v1x), e0y = __fsub_rn(v2y, v1y);
    float e1x = __fsub_rn(v0x, v2x), e1y = __fsub_rn(v0y, v2y);
    float e2x = __fsub_rn(v1x, v0x), e2y = __fsub_rn(v1y, v0y);
    float a0 = __fmul_rn(__fsub_rn(px, v1x), e0y);
    float a1 = __fmul_rn(__fsub_rn(px, v2x), e1y);
    float a2 = __fmul_rn(__fsub_rn(px, v0x), e2y);
    unsigned m = 0;
    #pragma unroll
    for (int k = 0; k < 4; ++k) {
        float py = (float)(2 * (ybase + 4 * k) + 1) * 0.00390625f - 1.0f;
        float w0 = __fsub_rn(a0, __fmul_rn(__fsub_rn(py, v1y), e0x));
        float w1 = __fsub_rn(a1, __fmul_rn(__fsub_rn(py, v2y), e1x));
        float w2 = __fsub_rn(a2, __fmul_rn(__fsub_rn(py, v0y), e2x));
        float mn = fminf(w0, fminf(w1, w2));
        float mx = fmaxf(w0, fmaxf(w1, w2));
        if ((mn >= 0.f) || (mx <= 0.f)) m |= 1u << k;
    }
    return m;
}

// Wave-split raster: wave w takes list entries w, w+4, w+8, ... (4x less
// redundancy than all-waves-walk-all). Eager x4 batched loads (8 float4s in
// flight) break the load-latency chain. Per-wave full-coverage early skip.
__device__ __forceinline__ void raster_ws(const int* __restrict__ lst, int n,
        const FaceRec* __restrict__ rb, float px, int ybase, int w,
        unsigned& mask) {
    int i = w;
    for (; i + 12 < n; i += 16) {
        if (__all((int)(mask == 0xFu))) return;
        int f0 = lst[i], f1 = lst[i + 4], f2 = lst[i + 8], f3 = lst[i + 12];
        float4 a0 = rb[f0].a, b0 = rb[f0].b;
        float4 a1 = rb[f1].a, b1 = rb[f1].b;
        float4 a2 = rb[f2].a, b2 = rb[f2].b;
        float4 a3 = rb[f3].a, b3 = rb[f3].b;
        mask |= test4(a0, b0, px, ybase);
        mask |= test4(a1, b1, px, ybase);
        mask |= test4(a2, b2, px, ybase);
        mask |= test4(a3, b3, px, ybase);
    }
    for (; i < n; i += 4) {
        int fid = lst[i];
        float4 ra = rb[fid].a, rc = rb[fid].b;
        mask |= test4(ra, rc, px, ybase);
    }
}

// SUBT blocks per 16x16 tile; block `sub` scans face-quads [sub*Q, sub*Q+Q).
// Per 1024-face chunk, three dense phases:
//   A: bbox prefilter (int4, no global vert loads) -> LDS survivor list
//   B: cooperative classify, 1 face/thread (full lane utilization):
//      dominates -> tile=1; outside -> drop; partial -> LDS list L2
//   C: wave-split exact raster of L2 (4-bit row mask per lane)
// Output pre-zeroed by prep; covered pixels stored conditionally.
__global__ __launch_bounds__(256) void tile_kernel(
        const FaceRec* __restrict__ recs, const int4* __restrict__ bbq,
        float* __restrict__ out, int B, int F, int Fp) {
    __shared__ int L1[CAP];
    __shared__ int L2[CAP];
    __shared__ int s_c1, s_c2, s_dom, s_cov[64];
    int bid  = blockIdx.x;
    int tile = bid / SUBT;
    int sub  = bid - tile * SUBT;
    int b = tile >> 8, t = tile & 255;
    int tx0 = (t & 15) << 4, ty0 = (t >> 4) << 4;
    int tid = threadIdx.x;
    int lane = tid & 63, w = tid >> 6;
    int col = lane & 15, r0 = lane >> 4;
    // pixel centers (2k+1)/256 - 1, exactly representable in fp32
    float px = (float)(2 * (tx0 + col) + 1) * 0.00390625f - 1.0f;
    int ybase = ty0 + r0;                 // this lane's rows: ybase + 4k
    float cx0 = (float)(2 * tx0 + 1) * 0.00390625f - 1.0f;
    float cy0 = (float)(2 * ty0 + 1) * 0.00390625f - 1.0f;
    int txm = tx0 + 15, tym = ty0 + 15;
    const float EXT = 0.1171875f;  // 30/256: span of the tile's pixel centers
    const FaceRec* rb = recs + (size_t)b * Fp;
    int F4 = Fp >> 2;
    const int4* qb = bbq + (size_t)b * F4;
    int Q = (F4 + SUBT - 1) / SUBT;
    int qlo = sub * Q;
    int qhi = min(F4, qlo + Q);
    if (tid < 64) s_cov[tid] = 0;
    unsigned mask = 0;
    bool dom = false;

    for (int q0 = qlo; q0 < qhi; q0 += 256) {
        if (tid == 0) { s_c1 = 0; s_c2 = 0; s_dom = 0; }
        __syncthreads();                  // resets visible; prev raster done
        // --- Phase A: bbox prefilter -> L1 (no vert loads) ---
        int q = q0 + tid;
        if (q < qhi) {
            int4 bb4 = qb[q];
            int fbase = q << 2;
            #pragma unroll
            for (int k = 0; k < 4; ++k) {
                int bb = (k == 0) ? bb4.x : (k == 1) ? bb4.y
                       : (k == 2) ? bb4.z : bb4.w;
                int ix0 = bb & 255, ix1 = (bb >> 8) & 255;
                int iy0 = (bb >> 16) & 255, iy1 = (bb >> 24) & 255;
                if (ix0 <= txm && ix1 >= tx0 && iy0 <= tym && iy1 >= ty0) {
                    int s = atomicAdd(&s_c1, 1);   // <= 1024/chunk == CAP
                    L1[s] = fbase + k;
                }
            }
        }
        __syncthreads();                  // L1 complete
        // --- Phase B: dense classify, 1 face/thread ---
        int n1 = s_c1;
        for (int i = tid; i < n1; i += 256) {
            int fid = L1[i];
            float4 ra = rb[fid].a;
            float4 rc = rb[fid].b;
            float v0x = ra.x, v0y = ra.y, v1x = ra.z, v1y = ra.w;
            float v2x = rc.x, v2y = rc.y;
            float e0x = __fsub_rn(v2x, v1x), e0y = __fsub_rn(v2y, v1y);
            float e1x = __fsub_rn(v0x, v2x), e1y = __fsub_rn(v0y, v2y);
            float e2x = __fsub_rn(v1x, v0x), e2y = __fsub_rn(v1y, v0y);
            // edge value at tile-corner pixel center; affine -> interval bound
            float w0 = (cx0 - v1x) * e0y - (cy0 - v1y) * e0x;
            float w1 = (cx0 - v2x) * e1y - (cy0 - v2y) * e1x;
            float w2 = (cx0 - v0x) * e2y - (cy0 - v0y) * e2x;
            float ax0 = EXT * e0y, ay0 = -EXT * e0x;
            float ax1 = EXT * e1y, ay1 = -EXT * e1x;
            float ax2 = EXT * e2y, ay2 = -EXT * e2x;
            float mn0 = w0 + fminf(ax0, 0.f) + fminf(ay0, 0.f);
            float mx0 = w0 + fmaxf(ax0, 0.f) + fmaxf(ay0, 0.f);
            float mn1 = w1 + fminf(ax1, 0.f) + fminf(ay1, 0.f);
            float mx1 = w1 + fmaxf(ax1, 0.f) + fmaxf(ay1, 0.f);
            float mn2 = w2 + fminf(ax2, 0.f) + fminf(ay2, 0.f);
            float mx2 = w2 + fmaxf(ax2, 0.f) + fmaxf(ay2, 0.f);
            bool posIn = fminf(mn0, fminf(mn1, mn2)) >  DELTA;
            bool negIn = fmaxf(mx0, fmaxf(mx1, mx2)) < -DELTA;
            if (posIn || negIn) {
                s_dom = 1;                 // benign race: all writers store 1
            } else {
                bool outz = (fminf(mx0, fminf(mx1, mx2)) < -DELTA) &&
                            (fmaxf(mn0, fmaxf(mn1, mn2)) >  DELTA);
                if (!outz) {
                    int s = atomicAdd(&s_c2, 1);   // <= n1 <= CAP
                    L2[s] = fid;
                }
            }
        }
        __syncthreads();                  // L2 + dom flag complete
        int n2 = s_c2;
        if (s_dom) { dom = true; break; } // uniform (read after barrier)
        // --- Phase C: wave-split exact raster ---
        raster_ws(L2, n2, rb, px, ybase, w, mask);
        __syncthreads();                  // raster reads done before next reset
    }

    size_t outB = (size_t)b << 16;
    if (dom) {
        out[outB + (ty0 + (tid >> 4)) * IMG + tx0 + (tid & 15)] = 1.0f;
        return;
    }
    atomicOr(&s_cov[lane], (int)mask);
    __syncthreads();
    int row = tid >> 4, oc = tid & 15;
    int li = oc | ((row & 3) << 4), k = row >> 2;
    if ((s_cov[li] >> k) & 1)
        out[outB + (ty0 + row) * IMG + tx0 + oc] = 1.0f;
}

// ---------------- Fallback path (proven) if workspace too small ----------------
__global__ void init_kernel(const float* __restrict__ verts,
                            const float* __restrict__ cams,
                            float4* __restrict__ out4, int n4,
                            float2* __restrict__ ndc, int BV, int V) {
    int i = blockIdx.x * blockDim.x + threadIdx.x;
    if (i < n4) out4[i] = make_float4(0.f, 0.f, 0.f, 0.f);
    if (i < BV) {
        int b = i / V;
        float f  = __fadd_rn(__fmul_rn(1.0f, cams[b * 3 + 0]), 0.0f);
        float cx = cams[b * 3 + 1];
        float cy = cams[b * 3 + 2];
        float image_size = __fmul_rn(cams[1], 2.0f);
        float x = verts[3 * i + 0];
        float y = verts[3 * i + 1];
        float z = __fadd_rn(verts[3 * i + 2], 0.0f);
        float px = __fadd_rn(__fdiv_rn(__fmul_rn(f, x), z), cx);
        float py = __fadd_rn(__fdiv_rn(__fmul_rn(f, y), z), cy);
        float nx = __fsub_rn(__fmul_rn(__fdiv_rn(px, image_size), 2.0f), 1.0f);
        float ny = __fsub_rn(__fmul_rn(__fdiv_rn(py, image_size), 2.0f), 1.0f);
        ndc[i] = make_float2(nx, ny);
    }
}

__global__ __launch_bounds__(256) void raster_kernel(
        const float2* __restrict__ ndc, const int* __restrict__ faces,
        float* __restrict__ out, int B, int V, int F) {
    int gid  = blockIdx.x * blockDim.x + threadIdx.x;
    int wave = gid >> 6;
    int lane = gid & 63;
    int widx = wave >> 2;
    int sub  = wave & (SPLIT - 1);
    if (widx >= B * F) return;
    int b  = widx / F;
    const int* fp = faces + (size_t)widx * 3;
    const float2* nb = ndc + (size_t)b * V;
    float2 v0 = nb[fp[0]];
    float2 v1 = nb[fp[1]];
    float2 v2 = nb[fp[2]];
    float area = __fsub_rn(
        __fmul_rn(__fsub_rn(v1.x, v0.x), __fsub_rn(v2.y, v0.y)),
        __fmul_rn(__fsub_rn(v1.y, v0.y), __fsub_rn(v2.x, v0.x)));
    if (!(fabsf(area) > 1e-12f)) return;
    float xmn = fminf(v0.x, fminf(v1.x, v2.x));
    float xmx = fmaxf(v0.x, fmaxf(v1.x, v2.x));
    float ymn = fminf(v0.y, fminf(v1.y, v2.y));
    float ymx = fmaxf(v0.y, fmaxf(v1.y, v2.y));
    int ix0 = max(0,       (int)floorf(xmn * 128.0f + 127.5f) - 1);
    int ix1 = min(IMG - 1, (int)ceilf (xmx * 128.0f + 127.5f) + 1);
    int iy0 = max(0,       (int)floorf(ymn * 128.0f + 127.5f) - 1);
    int iy1 = min(IMG - 1, (int)ceilf (ymx * 128.0f + 127.5f) + 1);
    if (ix1 < ix0 || iy1 < iy0) return;
    int W = ix1 - ix0 + 1, H = iy1 - iy0 + 1;
    int tws = 6, bestIt = ((W + 63) >> 6) * H;
    int it;
    it = ((W + 31) >> 5) * ((H + 1) >> 1); if (it < bestIt) { bestIt = it; tws = 5; }
    it = ((W + 15) >> 4) * ((H + 3) >> 2); if (it < bestIt) { bestIt = it; tws = 4; }
    it = ((W + 7)  >> 3) * ((H + 7) >> 3); if (it < bestIt) { bestIt = it; tws = 3; }
    int TW = 1 << tws, TH = 64 >> tws;
    int dx = lane & (TW - 1), dy = lane >> tws;
    float e0x = __fsub_rn(v2.x, v1.x), e0y = __fsub_rn(v2.y, v1.y);
    float e1x = __fsub_rn(v0.x, v2.x), e1y = __fsub_rn(v0.y, v2.y);
    float e2x = __fsub_rn(v1.x, v0.x), e2y = __fsub_rn(v1.y, v0.y);
    float* outb = out + (size_t)b * IMG * IMG;
    float pxStep = (float)TW * 0.0078125f;
    for (int ty = iy0 + sub * TH; ty <= iy1; ty += SPLIT * TH) {
        int y = ty + dy;
        bool yok = (y <= iy1);
        float py = (float)(2 * y + 1) * 0.00390625f - 1.0f;
        float t0 = __fmul_rn(__fsub_rn(py, v1.y), e0x);
        float t1 = __fmul_rn(__fsub_rn(py, v2.y), e1x);
        float t2 = __fmul_rn(__fsub_rn(py, v0.y), e2x);
        float* p = outb + y * IMG + ix0 + dx;
        int x = ix0 + dx;
        float px = (float)(2 * x + 1) * 0.00390625f - 1.0f;
        for (int tx = ix0; tx <= ix1; tx += TW) {
            float w0 = __fsub_rn(__fmul_rn(__fsub_rn(px, v1.x), e0y), t0);
            float w1 = __fsub_rn(__fmul_rn(__fsub_rn(px, v2.x), e1y), t1);
            float w2 = __fsub_rn(__fmul_rn(__fsub_rn(px, v0.x), e2y), t2);
            float mn = fminf(w0, fminf(w1, w2));
            float mx = fmaxf(w0, fmaxf(w1, w2));
            bool inside = (mn >= 0.f) | (mx <= 0.f);
            if (inside & yok & (x <= ix1)) *p = 1.0f;
            px += pxStep;
            x  += TW;
            p  += TW;
        }
    }
}

extern "C" void kernel_launch(void* const* d_in, const int* in_sizes, int n_in,
                              void* d_out, int out_size, void* d_ws, size_t ws_size,
                              hipStream_t stream) {
    const float* verts = (const float*)d_in[0];
    const int*   faces = (const int*)d_in[1];
    const float* cams  = (const float*)d_in[2];
    float* out = (float*)d_out;

    int B = in_sizes[2] / 3;
    int V = in_sizes[0] / (3 * B);
    int F = in_sizes[1] / (3 * B);
    int Fp = (F + 3) & ~3;               // pad to int4-quad multiple

    size_t recsB = (size_t)B * Fp * sizeof(FaceRec);
    size_t bbB   = (size_t)B * Fp * sizeof(int);
    if (ws_size >= recsB + bbB) {
        FaceRec* recs = (FaceRec*)d_ws;
        int* bbA = (int*)((char*)d_ws + recsB);   // recsB is 16B-aligned
        int n4 = out_size / 4;
        int nthr = B * Fp > n4 ? B * Fp : n4;
        hipLaunchKernelGGL(prep_kernel, dim3((nthr + 255) / 256), dim3(256), 0,
                           stream, verts, faces, cams, recs, bbA,
                           (float4*)d_out, n4, B, V, F, Fp);
        hipLaunchKernelGGL(tile_kernel, dim3(B * 256 * SUBT), dim3(256), 0,
                           stream, recs, (const int4*)bbA, out, B, F, Fp);
    } else {
        float2* ndc = (float2*)d_ws;
        int n4 = out_size / 4;
        int initThreads = n4 > B * V ? n4 : B * V;
        hipLaunchKernelGGL(init_kernel, dim3((initThreads + 255) / 256), dim3(256), 0,
                           stream, verts, cams, (float4*)d_out, n4, ndc, B * V, V);
        long long nthreads = (long long)B * F * SPLIT * 64;
        hipLaunchKernelGGL(raster_kernel, dim3((int)((nthreads + 255) / 256)),
                           dim3(256), 0, stream, ndc, faces, out, B, V, F);
    }
}